// Round 9
// baseline (255.868 us; speedup 1.0000x reference)
//
#include <hip/hip_runtime.h>

// Blocks SNN forward: T=1024, TB=8, B=32, N=1024.
// R16: time-relay with C=4 block chunks per hop (32 hops instead of 128),
// seqlock carry handoff, sleeping spinners.
//
// R15 measured ~1520cy/hop at C=1 (81.5us). Decomposition: hop overhead
// H (~700-1000cy: poll-detect + ma-read + ds_write+lgkm+pk-write
// visibility + spinner issue contention) is paid PER HOP; math M
// (~500-600cy: f64 header chain + 8-FMA Horner at ~32cy dep latency) is
// paid PER BLOCK. Serial time = (128/C)*H + 128*M. C=4 cuts 96 hop
// overheads off the chain while leaving math untouched.
//   * Seqlock poll: each iteration volatile-reads pk THEN m,a (same-wave
//     DS ops process in order). pk==gen implies the ma reads in the SAME
//     iteration saw the new data (writer: ma-writes -> lgkmcnt(0) ->
//     pk-write). Saves the post-detect ma round-trip.
//   * s_sleep(1) between polls: spinners yield issue slots + LDS BW so
//     the one working wave's f64 chain runs uncontended.
//   * Per wave-hop vmem: [8 DMAs next-superround][32 spike stores]; at
//     next hop top vmcnt(32) retires exactly the 8 oldest (the DMAs).
//     Single-buffered stg is race-free: cur reads drained (lgkmcnt(0))
//     before the DMA overwriting the tiles is issued.
// Math verbatim from R8-R15 (absmax 0.0 proven). LDS 74KB -> 2 WG/CU.

constexpr int T_LEN = 1024;
constexpr int TB    = 8;
constexpr int NBLK  = T_LEN / TB;   // 128
constexpr int BATCH = 32;
constexpr int NOUT  = 1024;
constexpr int BN    = BATCH * NOUT; // 32768 chains
constexpr int W     = 8;            // relay waves per WG
constexpr int C     = 4;            // blocks per hop
constexpr int NSR   = NBLK / (W * C); // 4 superrounds
constexpr int CRING = 8;            // carry ring slots (hop-indexed)

__device__ __forceinline__ void dma16(const float* g, float* l) {
    __builtin_amdgcn_global_load_lds(
        (const __attribute__((address_space(1))) void*)g,
        (__attribute__((address_space(3))) void*)l, 16, 0, 0);
}

__global__ __launch_bounds__(512, 4)
void snn_blocks_kernel(const float* __restrict__ x,
                       const float* __restrict__ beta_raw,
                       const float* __restrict__ p_raw,
                       const float* __restrict__ b_raw,
                       float* __restrict__ out)
{
    __shared__ float    stg[W][C][TB * 64];      // 64KB per-wave staging
    __shared__ double   carry_ma[CRING][2 * 64]; // 8KB: m,a per lane
    __shared__ unsigned carry_pk[CRING][64];     // 2KB: gen|maskf|firstp

    const int tid  = threadIdx.x;
    const int lane = tid & 63;
    const int w    = tid >> 6;              // relay wave id 0..7
    const int wg0  = blockIdx.x * 64;       // 64-chain stripe offset
    const int gid  = wg0 + lane;            // = b*NOUT + n
    const int n    = gid & (NOUT - 1);

    // clamped properties (f64) — identical for all 8 waves of the WG
    double beta = (double)beta_raw[n];
    beta = beta < 0.001 ? 0.001 : (beta > 0.999 ? 0.999 : beta);
    double p = fabs((double)p_raw[n]);
    p = p > 0.999 ? 0.999 : p;
    double bb = fabs((double)b_raw[n]);
    bb = bb < 0.001 ? 0.001 : (bb > 1.0 ? 1.0 : bb);
    const double inv_p = 1.0 / p;

    double ppow[9];
    ppow[0] = 1.0;
#pragma unroll
    for (int i = 1; i <= 8; ++i) ppow[i] = ppow[i - 1] * p;
    double bbp[8];
#pragma unroll
    for (int t = 0; t < 8; ++t) bbp[t] = bb * ppow[t + 1];
    const double pp2 = ppow[2], pp4 = ppow[4], pp8 = ppow[8];

    // zero the generation words (512 words, 512 threads)
    (&carry_pk[0][0])[tid] = 0u;

    // prologue: each wave DMAs its superround-0 chunk (blocks w*C..w*C+3).
    // DMA HW layout (R10-proven): lane p writes LDS bytes [16p,16p+16) ==
    // rows (p>>4) [+4 for op 2], cols (p&15)*4..+3.
    const float* xb_dma =
        x + (ptrdiff_t)(lane >> 4) * BN + wg0 + (lane & 15) * 4;
#pragma unroll
    for (int c = 0; c < C; ++c) {
        const int b = w * C + c;
        const float* g = xb_dma + (ptrdiff_t)(b * TB) * BN;
        dma16(g,          &stg[w][c][0]);
        dma16(g + 4 * BN, &stg[w][c][256]);
    }
    __syncthreads();   // drains prologue DMA + pk zero-init visible

    float* ob = out + gid;

#pragma unroll 1
    for (int r = 0; r < NSR; ++r) {
        const int h  = r * W + w;           // my hop index (0..31)
        const int b0 = h * C;               // first block of my chunk

        // my superround-r DMAs (issued at hop r-1, oldest of <=40
        // outstanding) must be retired before reading stg.
        if (r > 0)
            asm volatile("s_waitcnt vmcnt(32)" ::: "memory");

        // pre-read the whole chunk into registers (off critical path)
        float cur[C][8];
#pragma unroll
        for (int c = 0; c < C; ++c)
#pragma unroll
            for (int t = 0; t < 8; ++t)
                cur[c][t] = stg[w][c][t * 64 + lane];
        asm volatile("s_waitcnt lgkmcnt(0)" ::: "memory"); // reads done

        // issue next-superround DMAs into the (now free) same tiles
        if (r + 1 < NSR) {
#pragma unroll
            for (int c = 0; c < C; ++c) {
                const int b = (h + W) * C + c;
                const float* g = xb_dma + (ptrdiff_t)(b * TB) * BN;
                dma16(g,          &stg[w][c][0]);
                dma16(g + 4 * BN, &stg[w][c][256]);
            }
        }

        // ---- acquire carry for hop h (seqlock; sleep between polls) ----
        double m, a;
        int maskf, firstp;
        if (h == 0) {
            m = 0.0; a = 0.0; maskf = 0; firstp = 0;
        } else {
            const int slot = h & (CRING - 1);
            volatile const unsigned* vpk = &carry_pk[slot][lane];
            volatile const double*   vma = &carry_ma[slot][2 * lane];
            unsigned pk;
            for (;;) {
                pk = *vpk;            // pk read FIRST (same-wave DS order)
                m  = vma[0];          // then data: valid iff pk matches
                a  = vma[1];
                if ((pk >> 8) == (unsigned)h) break;
                __builtin_amdgcn_s_sleep(1);
            }
            asm volatile("" ::: "memory");
            maskf  = (pk >> 4) & 1;
            firstp = pk & 7;
        }

        __builtin_amdgcn_s_setprio(1);

        int fmk[C], ffp[C];
        // ---- C blocks of verbatim math, carry in registers ----
#pragma unroll
        for (int c = 0; c < C; ++c) {
            // header: adaptation update from prev-block stats
            double pf1 = p;                        // -> p^(firstp+1)
            pf1 *= (firstp & 1) ? p   : 1.0;
            pf1 *= (firstp & 2) ? pp2 : 1.0;
            pf1 *= (firstp & 4) ? pp4 : 1.0;
            const int dsteps = firstp ^ 7;         // 7 - firstp
            double pd = (dsteps & 1) ? p : 1.0;
            pd *= (dsteps & 2) ? pp2 : 1.0;
            pd *= (dsteps & 4) ? pp4 : 1.0;
            const double new_a = (a * pf1 + inv_p) * pd;
            double vinit;
            if (maskf) { a = new_a;   vinit = 0.0; }  // v_init = 0
            else       { a = pp8 * a; vinit = m;   }  // keep int_mem

            // refractory mask: prev z[t]==0 <=> t < firstp (when maskf)
            const int zmask = maskf ? ((1 << firstp) - 1) : 0;

            int fbits = 0;
            double mm = vinit;
#pragma unroll
            for (int t = 0; t < 8; ++t) {
                const float xf = ((zmask >> t) & 1) ? 0.0f : cur[c][t];
                mm = beta * mm + (double)xf;           // causal decayed sum
                const double vth = 1.0 + bbp[t] * a;   // 1 + bb*p^(t+1)*a
                fbits |= (mm - vth > 0.0) ? (1 << t) : 0;  // heaviside
            }
            m = mm;
            maskf  = (fbits != 0) ? 1 : 0;
            firstp = fbits ? __builtin_ctz(fbits) : 0;
            fmk[c] = maskf;
            ffp[c] = firstp;
        }

        // ---- hand off carry for hop h+1 ----
        {
            const int s2 = (h + 1) & (CRING - 1);
            carry_ma[s2][2 * lane]     = m;
            carry_ma[s2][2 * lane + 1] = a;
            asm volatile("s_waitcnt lgkmcnt(0)" ::: "memory"); // data first
            carry_pk[s2][lane] =
                ((unsigned)(h + 1) << 8) | (maskf << 4) | firstp;
        }
        __builtin_amdgcn_s_setprio(0);
        asm volatile("" ::: "memory");

        // ---- spike stores for the chunk (one-hot; fire-and-forget) ----
#pragma unroll
        for (int c = 0; c < C; ++c) {
            const int b = b0 + c;
#pragma unroll
            for (int t = 0; t < 8; ++t) {
                const float sv = (fmk[c] && t == ffp[c]) ? 1.0f : 0.0f;
                ob[(ptrdiff_t)(b * TB + t) * BN] = sv;
            }
        }
        asm volatile("" ::: "memory");
    }
}

extern "C" void kernel_launch(void* const* d_in, const int* in_sizes, int n_in,
                              void* d_out, int out_size, void* d_ws, size_t ws_size,
                              hipStream_t stream) {
    const float* x        = (const float*)d_in[0];
    const float* beta_raw = (const float*)d_in[1];
    const float* p_raw    = (const float*)d_in[2];
    const float* b_raw    = (const float*)d_in[3];
    float* out            = (float*)d_out;

    dim3 grid(BN / 64);   // 512 WGs x 8 relay waves
    dim3 block(512);
    snn_blocks_kernel<<<grid, block, 0, stream>>>(x, beta_raw, p_raw, b_raw, out);
}